// Round 11
// baseline (34.148 us; speedup 1.0000x reference)
//
#include <hip/hip_runtime.h>

#define NB 64
#define NC 206
#define N (NB * NC)          // 13184
#define M_HARM 15            // cosine-quadrature harmonics
#define DELTA 0.32f          // quadrature spacing
#define NVALS (7 + 4 * M_HARM)   // 67 reduced values
#define PI_D 3.14159265358979323846

// Separable expansion (exact identities + trapezoid quadrature):
//   softplus(x) = x/2 + ln2 + log cosh(x/2)
//   log cosh(x/2) = \int_0^inf (1-cos wx)/(w sinh(pi w)) dw
//     ~= (D/(4pi)) x^2 + sum_k c_k (1 - cos(w_k x)),  w_k = k*D,
//        c_k = D/(w_k sinh(pi w_k))
// With x = p_neg - p_pos, every term factorizes into per-class weighted
// moments: S=Σw, Sp=Σwp, Sp2=Σwp², C_k=Σw cos(w_k p), E_k=Σw sin(w_k p).
// One pass over N elements -> 67 moments -> closed-form combine. O(N*M).
__global__ __launch_bounds__(1024) void auc_moments_kernel(
    const float* __restrict__ preds,
    const float* __restrict__ sw,
    const int* __restrict__ labels,
    float* __restrict__ out)
{
    const int tid  = threadIdx.x;
    const int lane = tid & 63;
    const int wave = tid >> 6;           // 0..15

    float cnt = 0.f;                     // npos (exact in f32, < 2^24)
    float S = 0.f, Sp = 0.f, Sp2 = 0.f;  // positive-class moments
    float T = 0.f, Tp = 0.f, Tp2 = 0.f;  // negative-class moments
    float Cp[M_HARM], Ep[M_HARM], Cn[M_HARM], En[M_HARM];
    #pragma unroll
    for (int k = 0; k < M_HARM; ++k) { Cp[k] = Ep[k] = Cn[k] = En[k] = 0.f; }

    for (int i = tid; i < N; i += 1024) {
        float p = preds[i];
        int   l = labels[i];             // {0,1}
        float w = sw[i / NC];
        float wp = (l == 1) ? w : 0.f;
        float wn = w - wp;
        cnt += (float)l;
        S  += wp; Sp  = fmaf(wp, p, Sp);  Sp2 = fmaf(wp * p, p, Sp2);
        T  += wn; Tp  = fmaf(wn, p, Tp);  Tp2 = fmaf(wn * p, p, Tp2);

        float sth, cth;
        __sincosf(DELTA * p, &sth, &cth);
        float t2 = 2.f * cth;
        float ckm1 = 1.f, skm1 = 0.f;    // cos/sin(0)
        float ck = cth, sk = sth;        // cos/sin(theta)
        #pragma unroll
        for (int k = 0; k < M_HARM; ++k) {
            Cp[k] = fmaf(wp, ck, Cp[k]);
            Ep[k] = fmaf(wp, sk, Ep[k]);
            Cn[k] = fmaf(wn, ck, Cn[k]);
            En[k] = fmaf(wn, sk, En[k]);
            float cnx = fmaf(t2, ck, -ckm1);   // Chebyshev recurrence
            float snx = fmaf(t2, sk, -skm1);
            ckm1 = ck; skm1 = sk; ck = cnx; sk = snx;
        }
    }

    // pack (static indices only — fully unrolled)
    float v[NVALS];
    v[0] = cnt; v[1] = S; v[2] = Sp; v[3] = Sp2;
    v[4] = T;   v[5] = Tp; v[6] = Tp2;
    #pragma unroll
    for (int k = 0; k < M_HARM; ++k) {
        v[7 + k]              = Cp[k];
        v[7 + M_HARM + k]     = Ep[k];
        v[7 + 2 * M_HARM + k] = Cn[k];
        v[7 + 3 * M_HARM + k] = En[k];
    }

    // wave reduce all 67 values (unrolled: static indexing, stays in VGPRs)
    #pragma unroll
    for (int q = 0; q < NVALS; ++q) {
        #pragma unroll
        for (int off = 32; off > 0; off >>= 1)
            v[q] += __shfl_down(v[q], off, 64);
    }

    __shared__ float red[16][NVALS];     // 4288 B
    if (lane == 0) {
        #pragma unroll
        for (int q = 0; q < NVALS; ++q) red[wave][q] = v[q];
    }
    __syncthreads();

    __shared__ double fin[NVALS];
    if (tid < NVALS) {
        double d = 0.0;
        #pragma unroll
        for (int w2 = 0; w2 < 16; ++w2) d += (double)red[w2][tid];
        fin[tid] = d;
    }
    __syncthreads();

    if (tid == 0) {
        const double D = (double)DELTA;
        double npos = fin[0];
        double S_ = fin[1], Sp_ = fin[2], Sp2_ = fin[3];
        double T_ = fin[4], Tp_ = fin[5], Tp2_ = fin[6];

        // linear + constant + quadratic (quadrature endpoint) terms
        double acc = 0.5 * (S_ * Tp_ - T_ * Sp_)
                   + 0.6931471805599453 * (S_ * T_)
                   + (D / (4.0 * PI_D)) * (S_ * Tp2_ + T_ * Sp2_ - 2.0 * Sp_ * Tp_);

        // cosine terms: sum_ij w_i w_j cos(w_k(p_j - p_i)) = Cp*Cn + Ep*En
        for (int k = 1; k <= M_HARM; ++k) {
            double wk  = D * (double)k;
            double ckk = D / (wk * sinh(PI_D * wk));
            double Cpk = fin[6 + k];
            double Epk = fin[6 + M_HARM + k];
            double Cnk = fin[6 + 2 * M_HARM + k];
            double Enk = fin[6 + 3 * M_HARM + k];
            acc += ckk * (S_ * T_ - Cpk * Cnk - Epk * Enk);
        }

        double nneg = (double)N - npos;
        out[0] = (float)(acc / (npos * nneg));
    }
}

extern "C" void kernel_launch(void* const* d_in, const int* in_sizes, int n_in,
                              void* d_out, int out_size, void* d_ws, size_t ws_size,
                              hipStream_t stream)
{
    const float* preds  = (const float*)d_in[0];
    const float* sw     = (const float*)d_in[1];
    const int*   labels = (const int*)d_in[2];
    float* out = (float*)d_out;

    auc_moments_kernel<<<1, 1024, 0, stream>>>(preds, sw, labels, out);
}

// Round 12
// 27.461 us; speedup vs baseline: 1.2435x; 1.2435x over previous
//
#include <hip/hip_runtime.h>

#define NB 64
#define NC 206
#define N (NB * NC)          // 13184
#define THREADS 512          // 8 waves -> 2 waves/SIMD -> 256-VGPR cap, no spill
#define M_HARM 15            // cosine-quadrature harmonics
#define DELTA 0.32f          // quadrature spacing
#define NVALS (7 + 4 * M_HARM)   // 67 reduced values
#define PI_D 3.14159265358979323846

// Separable expansion (exact identities + trapezoid quadrature):
//   softplus(x) = x/2 + ln2 + log cosh(x/2)
//   log cosh(x/2) = \int_0^inf (1-cos wx)/(w sinh(pi w)) dw
//     ~= (D/(4pi)) x^2 + sum_k c_k (1 - cos(w_k x)),  w_k = k*D,
//        c_k = D/(w_k sinh(pi w_k))
// With x = p_neg - p_pos, every term factorizes into per-class weighted
// moments: S=Σw, Sp=Σwp, Sp2=Σwp², C_k=Σw cos(w_k p), E_k=Σw sin(w_k p).
// One pass over N elements -> 67 moments -> closed-form combine. O(N*M).
// Verified round 11: absmax 0.0. This round only fixes the VGPR spill
// (1024-thread block capped waves at 128 VGPR; 512 threads allows 256).
__global__ __launch_bounds__(THREADS) void auc_moments_kernel(
    const float* __restrict__ preds,
    const float* __restrict__ sw,
    const int* __restrict__ labels,
    float* __restrict__ out)
{
    const int tid  = threadIdx.x;
    const int lane = tid & 63;
    const int wave = tid >> 6;           // 0..7

    float cnt = 0.f;                     // npos (exact in f32, < 2^24)
    float S = 0.f, Sp = 0.f, Sp2 = 0.f;  // positive-class moments
    float T = 0.f, Tp = 0.f, Tp2 = 0.f;  // negative-class moments
    float Cp[M_HARM], Ep[M_HARM], Cn[M_HARM], En[M_HARM];
    #pragma unroll
    for (int k = 0; k < M_HARM; ++k) { Cp[k] = Ep[k] = Cn[k] = En[k] = 0.f; }

    for (int i = tid; i < N; i += THREADS) {
        float p = preds[i];
        int   l = labels[i];             // {0,1}
        float w = sw[i / NC];
        float wp = (l == 1) ? w : 0.f;
        float wn = w - wp;
        cnt += (float)l;
        S  += wp; Sp  = fmaf(wp, p, Sp);  Sp2 = fmaf(wp * p, p, Sp2);
        T  += wn; Tp  = fmaf(wn, p, Tp);  Tp2 = fmaf(wn * p, p, Tp2);

        float sth, cth;
        __sincosf(DELTA * p, &sth, &cth);
        float t2 = 2.f * cth;
        float ckm1 = 1.f, skm1 = 0.f;    // cos/sin(0)
        float ck = cth, sk = sth;        // cos/sin(theta)
        #pragma unroll
        for (int k = 0; k < M_HARM; ++k) {
            Cp[k] = fmaf(wp, ck, Cp[k]);
            Ep[k] = fmaf(wp, sk, Ep[k]);
            Cn[k] = fmaf(wn, ck, Cn[k]);
            En[k] = fmaf(wn, sk, En[k]);
            float cnx = fmaf(t2, ck, -ckm1);   // Chebyshev recurrence
            float snx = fmaf(t2, sk, -skm1);
            ckm1 = ck; skm1 = sk; ck = cnx; sk = snx;
        }
    }

    // pack (static indices only — fully unrolled, stays in VGPRs)
    float v[NVALS];
    v[0] = cnt; v[1] = S; v[2] = Sp; v[3] = Sp2;
    v[4] = T;   v[5] = Tp; v[6] = Tp2;
    #pragma unroll
    for (int k = 0; k < M_HARM; ++k) {
        v[7 + k]              = Cp[k];
        v[7 + M_HARM + k]     = Ep[k];
        v[7 + 2 * M_HARM + k] = Cn[k];
        v[7 + 3 * M_HARM + k] = En[k];
    }

    // wave reduce all 67 values
    #pragma unroll
    for (int q = 0; q < NVALS; ++q) {
        #pragma unroll
        for (int off = 32; off > 0; off >>= 1)
            v[q] += __shfl_down(v[q], off, 64);
    }

    __shared__ float red[8][NVALS];      // 2144 B
    if (lane == 0) {
        #pragma unroll
        for (int q = 0; q < NVALS; ++q) red[wave][q] = v[q];
    }
    __syncthreads();

    __shared__ double fin[NVALS];
    if (tid < NVALS) {
        double d = 0.0;
        #pragma unroll
        for (int w2 = 0; w2 < 8; ++w2) d += (double)red[w2][tid];
        fin[tid] = d;
    }
    __syncthreads();

    if (tid == 0) {
        const double D = (double)DELTA;
        double npos = fin[0];
        double S_ = fin[1], Sp_ = fin[2], Sp2_ = fin[3];
        double T_ = fin[4], Tp_ = fin[5], Tp2_ = fin[6];

        // linear + constant + quadratic (quadrature endpoint) terms
        double acc = 0.5 * (S_ * Tp_ - T_ * Sp_)
                   + 0.6931471805599453 * (S_ * T_)
                   + (D / (4.0 * PI_D)) * (S_ * Tp2_ + T_ * Sp2_ - 2.0 * Sp_ * Tp_);

        // cosine terms: sum_ij w_i w_j cos(w_k(p_j - p_i)) = Cp*Cn + Ep*En
        for (int k = 1; k <= M_HARM; ++k) {
            double wk  = D * (double)k;
            double ckk = D / (wk * sinh(PI_D * wk));
            double Cpk = fin[6 + k];
            double Epk = fin[6 + M_HARM + k];
            double Cnk = fin[6 + 2 * M_HARM + k];
            double Enk = fin[6 + 3 * M_HARM + k];
            acc += ckk * (S_ * T_ - Cpk * Cnk - Epk * Enk);
        }

        double nneg = (double)N - npos;
        out[0] = (float)(acc / (npos * nneg));
    }
}

extern "C" void kernel_launch(void* const* d_in, const int* in_sizes, int n_in,
                              void* d_out, int out_size, void* d_ws, size_t ws_size,
                              hipStream_t stream)
{
    const float* preds  = (const float*)d_in[0];
    const float* sw     = (const float*)d_in[1];
    const int*   labels = (const int*)d_in[2];
    float* out = (float*)d_out;

    auc_moments_kernel<<<1, THREADS, 0, stream>>>(preds, sw, labels, out);
}

// Round 13
// 22.864 us; speedup vs baseline: 1.4936x; 1.2011x over previous
//
#include <hip/hip_runtime.h>

#define NB 64
#define NC 206
#define N (NB * NC)          // 13184
#define THREADS 512
#define GBLK 26              // ceil(N / 512) -> one element per thread
#define M_HARM 15            // cosine-quadrature harmonics
#define DELTA 0.32f          // quadrature spacing
#define NVALS (7 + 4 * M_HARM)   // 67 reduced values
#define PI_D 3.14159265358979323846

// Separable expansion (verified absmax 0.0 in rounds 11/12):
//   softplus(x) = x/2 + ln2 + log cosh(x/2)
//   log cosh(x/2) = (D/(4pi)) x^2 + sum_k c_k (1 - cos(w_k x)),  w_k = k*D,
//     c_k = D/(w_k sinh(pi w_k))      (trapezoid quadrature, M=15, D=0.32)
// With x = p_neg - p_pos every term factorizes into per-class weighted
// moments -> one pass over N elements, closed-form combine. O(N*M).
// This round: spread over 26 blocks (1 elem/thread) + tiny combine node.
struct Ws {
    float partial[GBLK][NVALS];   // unconditionally rewritten every call
};

__global__ __launch_bounds__(THREADS) void moments_kernel(
    const float* __restrict__ preds,
    const float* __restrict__ sw,
    const int* __restrict__ labels,
    float (*__restrict__ partial)[NVALS])
{
    const int tid  = threadIdx.x;
    const int lane = tid & 63;
    const int wave = tid >> 6;           // 0..7
    const int i    = blockIdx.x * THREADS + tid;

    // one element per thread
    float cnt = 0.f, S = 0.f, Sp = 0.f, Sp2 = 0.f, T = 0.f, Tp = 0.f, Tp2 = 0.f;
    float Cp[M_HARM], Ep[M_HARM], Cn[M_HARM], En[M_HARM];
    #pragma unroll
    for (int k = 0; k < M_HARM; ++k) { Cp[k] = Ep[k] = Cn[k] = En[k] = 0.f; }

    if (i < N) {
        float p = preds[i];
        int   l = labels[i];             // {0,1}
        float w = sw[i / NC];
        float wp = (l == 1) ? w : 0.f;
        float wn = w - wp;
        cnt = (float)l;
        S = wp; Sp = wp * p; Sp2 = wp * p * p;
        T = wn; Tp = wn * p; Tp2 = wn * p * p;

        float sth, cth;
        __sincosf(DELTA * p, &sth, &cth);
        float t2 = 2.f * cth;
        float ckm1 = 1.f, skm1 = 0.f;
        float ck = cth, sk = sth;
        #pragma unroll
        for (int k = 0; k < M_HARM; ++k) {
            Cp[k] = wp * ck; Ep[k] = wp * sk;
            Cn[k] = wn * ck; En[k] = wn * sk;
            float cnx = fmaf(t2, ck, -ckm1);   // Chebyshev recurrence
            float snx = fmaf(t2, sk, -skm1);
            ckm1 = ck; skm1 = sk; ck = cnx; sk = snx;
        }
    }

    float v[NVALS];
    v[0] = cnt; v[1] = S; v[2] = Sp; v[3] = Sp2;
    v[4] = T;   v[5] = Tp; v[6] = Tp2;
    #pragma unroll
    for (int k = 0; k < M_HARM; ++k) {
        v[7 + k]              = Cp[k];
        v[7 + M_HARM + k]     = Ep[k];
        v[7 + 2 * M_HARM + k] = Cn[k];
        v[7 + 3 * M_HARM + k] = En[k];
    }

    #pragma unroll
    for (int q = 0; q < NVALS; ++q) {
        #pragma unroll
        for (int off = 32; off > 0; off >>= 1)
            v[q] += __shfl_down(v[q], off, 64);
    }

    __shared__ float red[8][NVALS];
    if (lane == 0) {
        #pragma unroll
        for (int q = 0; q < NVALS; ++q) red[wave][q] = v[q];
    }
    __syncthreads();
    if (tid < NVALS) {
        float s = 0.f;
        #pragma unroll
        for (int w2 = 0; w2 < 8; ++w2) s += red[w2][tid];
        partial[blockIdx.x][tid] = s;
    }
}

__global__ __launch_bounds__(128) void combine_kernel(
    const float (*__restrict__ partial)[NVALS],
    float* __restrict__ out)
{
    __shared__ double fin[NVALS];
    const int tid = threadIdx.x;
    if (tid < NVALS) {
        double d = 0.0;
        #pragma unroll
        for (int b = 0; b < GBLK; ++b) d += (double)partial[b][tid];
        fin[tid] = d;
    }
    __syncthreads();

    if (tid == 0) {
        const double D = (double)DELTA;
        double npos = fin[0];
        double S_ = fin[1], Sp_ = fin[2], Sp2_ = fin[3];
        double T_ = fin[4], Tp_ = fin[5], Tp2_ = fin[6];

        double acc = 0.5 * (S_ * Tp_ - T_ * Sp_)
                   + 0.6931471805599453 * (S_ * T_)
                   + (D / (4.0 * PI_D)) * (S_ * Tp2_ + T_ * Sp2_ - 2.0 * Sp_ * Tp_);

        for (int k = 1; k <= M_HARM; ++k) {
            double wk  = D * (double)k;
            double ckk = D / (wk * sinh(PI_D * wk));
            double Cpk = fin[6 + k];
            double Epk = fin[6 + M_HARM + k];
            double Cnk = fin[6 + 2 * M_HARM + k];
            double Enk = fin[6 + 3 * M_HARM + k];
            acc += ckk * (S_ * T_ - Cpk * Cnk - Epk * Enk);
        }

        double nneg = (double)N - npos;
        out[0] = (float)(acc / (npos * nneg));
    }
}

extern "C" void kernel_launch(void* const* d_in, const int* in_sizes, int n_in,
                              void* d_out, int out_size, void* d_ws, size_t ws_size,
                              hipStream_t stream)
{
    const float* preds  = (const float*)d_in[0];
    const float* sw     = (const float*)d_in[1];
    const int*   labels = (const int*)d_in[2];
    float* out = (float*)d_out;
    Ws* ws = (Ws*)d_ws;

    moments_kernel<<<GBLK, THREADS, 0, stream>>>(preds, sw, labels, ws->partial);
    combine_kernel<<<1, 128, 0, stream>>>(
        (const float (*)[NVALS])ws->partial, out);
}

// Round 14
// 21.466 us; speedup vs baseline: 1.5908x; 1.0651x over previous
//
#include <hip/hip_runtime.h>

#define NB 64
#define NC 206
#define N (NB * NC)        // 13184
#define GX 13              // ceil(N / 1024) i-windows
#define NG8 26             // 8-wide groups per row = ceil(206/8)
#define NBLK (GX * NB)     // 832 blocks: x = i-window, y = sample row
#define LN2F 0.69314718056f

// Workspace: per-block partials only. All NBLK slots unconditionally
// rewritten every call — no zero-init, no atomics anywhere.
struct Ws {
    double partials[NBLK];
};

// contribution(i,j) = w_i * w_j * softplus(p_j - p_i),  i pos, j neg
//   = w_i * (w_row * ln2) * log2(1 + e^{p_j} * e^{-p_i})
// j masked via E_j = 0 (t=1 -> log-term 0); i compacted in-block.
// Best-measured configuration (round 10: 21.59 us, absmax 0.0).
__global__ __launch_bounds__(256) void pairs_kernel(
    const float* __restrict__ preds,
    const float* __restrict__ sw,
    const int* __restrict__ labels,
    double* __restrict__ partials)
{
    const int bx   = blockIdx.x;          // i-window (1024 raw elements)
    const int row  = blockIdx.y;          // j-row
    const int tid  = threadIdx.x;
    const int lane = tid & 63;
    const int wave = tid >> 6;

    __shared__ float sEGf[NG8 * 8];       // masked exp(p_neg), 0-padded to 208
    __shared__ float sF[1024], sPW[1024]; // compacted positives of this window
    __shared__ int   segCnt[16];          // per (k,wave) active counts
    __shared__ float wsum[4];

    // ---- stage this row's masked E values (threads 0..207) ----
    if (tid < NG8 * 8) {
        float e = 0.0f;
        if (tid < NC) {
            float p = preds[row * NC + tid];
            int   l = labels[row * NC + tid];
            e = (l == 0) ? __expf(p) : 0.0f;
        }
        sEGf[tid] = e;
    }

    // ---- deterministic in-block compaction of positive i's ----
    float pv[4]; float wv[4]; unsigned int rank[4]; bool act[4];
    unsigned long long pre = (1ull << lane) - 1ull;
    #pragma unroll
    for (int k = 0; k < 4; ++k) {
        int i = bx * 1024 + k * 256 + tid;
        bool a = false; float p = 0.0f, w = 0.0f;
        if (i < N) {
            p = preds[i];
            a = (labels[i] == 1);
            if (a) w = sw[i / NC];
        }
        unsigned long long ball = __ballot(a);
        if (lane == 0) segCnt[k * 4 + wave] = __popcll(ball);
        rank[k] = (unsigned int)__popcll(ball & pre);
        act[k] = a; pv[k] = p; wv[k] = w;
    }
    __syncthreads();

    int segBase[4]; int nAct = 0;
    {
        int run = 0;
        #pragma unroll
        for (int s = 0; s < 16; ++s) {
            int c = segCnt[s];                 // broadcast LDS read
            int k = s >> 2, wv_ = s & 3;
            if (wv_ == wave) segBase[k] = run; // base for my (k,wave) segment
            run += c;
        }
        nAct = run;
    }
    #pragma unroll
    for (int k = 0; k < 4; ++k) {
        if (act[k]) {
            int o = segBase[k] + (int)rank[k];
            sF[o]  = __expf(-pv[k]);
            sPW[o] = wv[k];
        }
    }
    __syncthreads();

    // ---- pair loop over compacted i's, 2-way ILP, 8-wide log groups ----
    const float4* sEG4 = (const float4*)sEGf;
    float a = 0.0f;
    for (int base = 0; base < nAct; base += 512) {
        int i0 = base + tid, i1 = base + 256 + tid;
        float F0 = 0.0f, P0 = 0.0f, F1 = 0.0f, P1 = 0.0f;
        if (i0 < nAct) { F0 = sF[i0]; P0 = sPW[i0]; }
        if (i1 < nAct) { F1 = sF[i1]; P1 = sPW[i1]; }
        float a0 = 0.0f, a1 = 0.0f;
        #pragma unroll 2
        for (int g = 0; g < NG8; ++g) {
            float4 e0 = sEG4[2 * g];          // broadcast ds_read_b128
            float4 e1 = sEG4[2 * g + 1];
            float m0, m1;
            {
                float t0 = fmaf(e0.x, F0, 1.0f), t1 = fmaf(e0.y, F0, 1.0f);
                float t2 = fmaf(e0.z, F0, 1.0f), t3 = fmaf(e0.w, F0, 1.0f);
                float t4 = fmaf(e1.x, F0, 1.0f), t5 = fmaf(e1.y, F0, 1.0f);
                float t6 = fmaf(e1.z, F0, 1.0f), t7 = fmaf(e1.w, F0, 1.0f);
                m0 = ((t0 * t1) * (t2 * t3)) * ((t4 * t5) * (t6 * t7));
            }
            {
                float t0 = fmaf(e0.x, F1, 1.0f), t1 = fmaf(e0.y, F1, 1.0f);
                float t2 = fmaf(e0.z, F1, 1.0f), t3 = fmaf(e0.w, F1, 1.0f);
                float t4 = fmaf(e1.x, F1, 1.0f), t5 = fmaf(e1.y, F1, 1.0f);
                float t6 = fmaf(e1.z, F1, 1.0f), t7 = fmaf(e1.w, F1, 1.0f);
                m1 = ((t0 * t1) * (t2 * t3)) * ((t4 * t5) * (t6 * t7));
            }
            a0 += __log2f(m0);               // max product ~1.8e31 < f32 max
            a1 += __log2f(m1);
        }
        a = fmaf(a0, P0, a);
        a = fmaf(a1, P1, a);
    }
    a *= sw[row] * LN2F;

    // ---- block reduce, one global write ----
    #pragma unroll
    for (int off = 32; off > 0; off >>= 1)
        a += __shfl_down(a, off, 64);
    if (lane == 0) wsum[wave] = a;
    __syncthreads();
    if (tid == 0)
        partials[row * GX + bx] = (double)(wsum[0] + wsum[1] + wsum[2] + wsum[3]);
}

// ---- reduce: sum partials + count labels for the denominator ----
__global__ __launch_bounds__(256) void reduce_kernel(
    const int* __restrict__ labels,
    const Ws* __restrict__ ws,
    float* __restrict__ out)
{
    const int lane = threadIdx.x & 63;
    const int wid  = threadIdx.x >> 6;

    double s = 0.0;
    for (int t = threadIdx.x; t < NBLK; t += 256)
        s += ws->partials[t];

    int pc = 0;
    const int4* l4 = (const int4*)labels;
    for (int t = threadIdx.x; t < N / 4; t += 256) {
        int4 v = l4[t];
        pc += v.x + v.y + v.z + v.w;
    }

    #pragma unroll
    for (int off = 32; off > 0; off >>= 1) {
        s  += __shfl_down(s, off, 64);
        pc += __shfl_down(pc, off, 64);
    }

    __shared__ double ds[4];
    __shared__ int    dp[4];
    if (lane == 0) { ds[wid] = s; dp[wid] = pc; }
    __syncthreads();
    if (threadIdx.x == 0) {
        double total = ds[0] + ds[1] + ds[2] + ds[3];
        int npos     = dp[0] + dp[1] + dp[2] + dp[3];
        double denom = (double)npos * (double)(N - npos);
        out[0] = (float)(total / denom);
    }
}

extern "C" void kernel_launch(void* const* d_in, const int* in_sizes, int n_in,
                              void* d_out, int out_size, void* d_ws, size_t ws_size,
                              hipStream_t stream)
{
    const float* preds  = (const float*)d_in[0];
    const float* sw     = (const float*)d_in[1];
    const int*   labels = (const int*)d_in[2];
    float* out = (float*)d_out;
    Ws* ws = (Ws*)d_ws;

    dim3 grid(GX, NB);
    pairs_kernel<<<grid, 256, 0, stream>>>(preds, sw, labels, ws->partials);

    reduce_kernel<<<1, 256, 0, stream>>>(labels, ws, out);
}